// Round 1
// baseline (175.409 us; speedup 1.0000x reference)
//
#include <hip/hip_runtime.h>

// Detail_loss: loss = 0.25/(98*258*256) * sum_{n,h,w} ( |D[h][w+1]-D[h][w-1]| + |D[h+1][w]-D[h-1][w]| )
// where D[n,h,w] = sum_c (infer - ref)[n,c,h,w], zero outside [0,256)^2.
// Derivation: conv kernels identical across channel pairs -> channel sum first;
// conv linear -> difference first; zero-pad boundary rows/cols contribute 0;
// both loss denominators equal 98*3*258*256; 3 identical output channels cancel the 3.

#define TH 32          // rows per strip
#define NSTRIP 8       // 256 / TH
#define NIMG 98        // 2*7*7
#define W 256
#define IMG_CH_STRIDE 65536   // 256*256

__global__ __launch_bounds__(256) void detail_loss_kernel(
    const float* __restrict__ x, const float* __restrict__ y,
    float* __restrict__ out) {
  __shared__ float Dsh[TH + 2][W];   // rows h0-1 .. h0+TH  (34 KB)

  const int n     = blockIdx.x / NSTRIP;
  const int strip = blockIdx.x % NSTRIP;
  const int h0    = strip * TH;
  const int tid   = threadIdx.x;          // 256 threads = 4 waves
  const int sub   = tid >> 6;             // wave id 0..3 -> row within group
  const int w4    = (tid & 63) << 2;      // float4 column offset, one wave covers a row

  const size_t img_off = (size_t)n * 3 * IMG_CH_STRIDE;
  const float* xb = x + img_off;
  const float* yb = y + img_off;

  // Phase 1: build channel-summed difference rows in LDS (float4, fully coalesced).
  for (int base = 0; base < TH + 2; base += 4) {
    int lr = base + sub;
    if (lr < TH + 2) {
      int row = h0 - 1 + lr;
      float4 d = make_float4(0.f, 0.f, 0.f, 0.f);
      if (row >= 0 && row < 256) {
        int off = row * W + w4;
        #pragma unroll
        for (int c = 0; c < 3; ++c) {
          float4 xv = *(const float4*)(xb + (size_t)c * IMG_CH_STRIDE + off);
          float4 yv = *(const float4*)(yb + (size_t)c * IMG_CH_STRIDE + off);
          d.x += xv.x - yv.x;
          d.y += xv.y - yv.y;
          d.z += xv.z - yv.z;
          d.w += xv.w - yv.w;
        }
      }
      *(float4*)&Dsh[lr][w4] = d;   // out-of-range rows stored as 0 (padding)
    }
  }
  __syncthreads();

  // Phase 2: each thread owns one column, walks TH rows.
  const int w = tid;
  float acc = 0.f;
  #pragma unroll 4
  for (int r = 0; r < TH; ++r) {
    const float* rowp = Dsh[r + 1];
    float dl = (w >= 1)     ? rowp[w - 1] : 0.f;   // col -1 is zero pad
    float dr = (w <= W - 2) ? rowp[w + 1] : 0.f;   // col 256 is zero pad
    float du = Dsh[r][w];
    float dd = Dsh[r + 2][w];
    acc += fabsf(dr - dl) + fabsf(dd - du);
  }

  // Wave reduction (64 lanes), then cross-wave via LDS.
  #pragma unroll
  for (int off = 32; off > 0; off >>= 1)
    acc += __shfl_down(acc, off, 64);

  __shared__ float wsum[4];
  if ((tid & 63) == 0) wsum[tid >> 6] = acc;
  __syncthreads();
  if (tid == 0) {
    float s = wsum[0] + wsum[1] + wsum[2] + wsum[3];
    // scale = 0.25 / (98*258*256)
    atomicAdd(out, s * (0.25f / 6472704.0f));
  }
}

extern "C" void kernel_launch(void* const* d_in, const int* in_sizes, int n_in,
                              void* d_out, int out_size, void* d_ws, size_t ws_size,
                              hipStream_t stream) {
  const float* infer = (const float*)d_in[0];
  const float* ref   = (const float*)d_in[1];
  float* out = (float*)d_out;

  hipMemsetAsync(out, 0, sizeof(float), stream);   // d_out is re-poisoned before every launch
  detail_loss_kernel<<<NIMG * NSTRIP, 256, 0, stream>>>(infer, ref, out);
}